// Round 7
// baseline (398.764 us; speedup 1.0000x reference)
//
#include <hip/hip_runtime.h>
#include <math.h>

// Problem constants
constexpr int E = 8, H = 1024, DFF = 2048, T = 4096;
constexpr int TR = 8192;            // total routed rows = T * topk
constexpr int MAXJ2 = TR / 256 + E; // 40: k2 jobs (256-row tiles)
constexpr int MAXJ3 = TR / 128 + E; // 72: k3 jobs (128-row tiles)

typedef __bf16 bf16x8 __attribute__((ext_vector_type(8)));
typedef __bf16 bf16x4 __attribute__((ext_vector_type(4)));
typedef float f32x4 __attribute__((ext_vector_type(4)));

__device__ __forceinline__ void gload16(const void* g, void* l) {
    __builtin_amdgcn_global_load_lds(
        (const __attribute__((address_space(1))) unsigned int*)g,
        (__attribute__((address_space(3))) unsigned int*)l, 16, 0, 0);
}

// ---------------- k0: fused conversions (gw,uw,x -> bf16, grid-stride) + affinity ----------------
constexpr int CONV_BLOCKS = 3072;
__global__ __launch_bounds__(256) void k0_fused(
    const float* __restrict__ x, const float* __restrict__ cent,
    const float* __restrict__ bias,
    int* __restrict__ se, float* __restrict__ sw,
    const float* __restrict__ gw, __bf16* __restrict__ gwb,
    const float* __restrict__ uw, __bf16* __restrict__ uwb,
    __bf16* __restrict__ xb, int w4, int x4, int* __restrict__ done) {
    __shared__ float cs[E * H];
    int tid = threadIdx.x;

    if (blockIdx.x == 0 && tid == 0) *done = 0;

    if (blockIdx.x >= 1024) {
        int total = 2 * w4 + x4;
        int stride = CONV_BLOCKS * 256;
        for (int i = (blockIdx.x - 1024) * 256 + tid; i < total; i += stride) {
            const float* in; __bf16* outp; int idx;
            if (i < w4) { in = gw; outp = gwb; idx = i; }
            else if (i < 2 * w4) { in = uw; outp = uwb; idx = i - w4; }
            else { in = x; outp = xb; idx = i - 2 * w4; }
            float4 v = ((const float4*)in)[idx];
            bf16x4 o = {(__bf16)v.x, (__bf16)v.y, (__bf16)v.z, (__bf16)v.w};
            ((bf16x4*)outp)[idx] = o;
        }
        return;
    }

    // affinity role
    for (int i = tid; i < E * H / 4; i += 256)
        ((float4*)cs)[i] = ((const float4*)cent)[i];
    __syncthreads();

    int wave = tid >> 6, lane = tid & 63;
    int t = blockIdx.x * 4 + wave;
    const float4* xr = (const float4*)(x + (size_t)t * H);
    float acc[E] = {};
    #pragma unroll
    for (int it = 0; it < 4; it++) {
        float4 xv = xr[lane + it * 64];
        #pragma unroll
        for (int e = 0; e < E; e++) {
            float4 cv = ((const float4*)(cs + e * H))[lane + it * 64];
            acc[e] = fmaf(xv.x, cv.x, acc[e]);
            acc[e] = fmaf(xv.y, cv.y, acc[e]);
            acc[e] = fmaf(xv.z, cv.z, acc[e]);
            acc[e] = fmaf(xv.w, cv.w, acc[e]);
        }
    }
    #pragma unroll
    for (int off = 32; off; off >>= 1)
        #pragma unroll
        for (int e = 0; e < E; e++) acc[e] += __shfl_down(acc[e], off);

    if (lane == 0) {
        float s[E];
        #pragma unroll
        for (int e = 0; e < E; e++)
            s[e] = 1.0f / (1.0f + expf(-acc[e])) + bias[e];
        int i0 = 0;
        for (int e = 1; e < E; e++) if (s[e] > s[i0]) i0 = e;
        int i1 = -1;
        for (int e = 0; e < E; e++) {
            if (e == i0) continue;
            if (i1 < 0 || s[e] > s[i1]) i1 = e;
        }
        float m = fmaxf(s[i0], s[i1]);
        float w0 = expf(s[i0] - m), w1 = expf(s[i1] - m);
        float inv = 1.0f / (w0 + w1);
        se[2 * t] = i0;     sw[2 * t] = w0 * inv;
        se[2 * t + 1] = i1; sw[2 * t + 1] = w1 * inv;
    }
}

// ---------------- k1b: per-expert partition + (last block) offsets/jobs ----------------
__global__ __launch_bounds__(1024) void k1b_partition(
    const int* __restrict__ se, int* __restrict__ token_list,
    int* __restrict__ sp, int* __restrict__ cnt,
    int* __restrict__ off, float* __restrict__ out_counts,
    int* __restrict__ jobs2, int* __restrict__ jobs3,
    int* __restrict__ njobs, int* __restrict__ done) {
    int e = blockIdx.x;
    int tid = threadIdx.x;
    int wave = tid >> 6, lane = tid & 63;
    __shared__ int wsum[16];
    int running = 0;
    for (int c0 = 0; c0 < 2 * T; c0 += 1024) {
        int i = c0 + tid;
        bool pred = (se[i] == e);
        unsigned long long mask = __ballot(pred);
        int pos_in_wave = __popcll(mask & ((1ull << lane) - 1ull));
        if (lane == 0) wsum[wave] = __popcll(mask);
        __syncthreads();
        int wbase = 0;
        #pragma unroll
        for (int w2 = 0; w2 < 16; w2++) {
            int v = wsum[w2];
            if (w2 < wave) wbase += v;
        }
        int total = 0;
        #pragma unroll
        for (int w2 = 0; w2 < 16; w2++) total += wsum[w2];
        if (pred) {
            int p = running + wbase + pos_in_wave;
            token_list[e * T + p] = i >> 1;
            sp[i] = p;
        }
        running += total;
        __syncthreads();
    }
    if (tid == 0) {
        __hip_atomic_store(&cnt[e], running, __ATOMIC_RELEASE, __HIP_MEMORY_SCOPE_AGENT);
        int prev = __hip_atomic_fetch_add(done, 1, __ATOMIC_ACQ_REL, __HIP_MEMORY_SCOPE_AGENT);
        if (prev == E - 1) {
            int acc = 0, nj2 = 0, nj3 = 0;
            for (int e2 = 0; e2 < E; e2++) {
                int c = __hip_atomic_load(&cnt[e2], __ATOMIC_ACQUIRE, __HIP_MEMORY_SCOPE_AGENT);
                off[e2] = acc; acc += c;
                out_counts[e2] = (float)c;
                int m2 = (c + 255) >> 8;
                for (int mt = 0; mt < m2; mt++) jobs2[nj2++] = e2 * 64 + mt;
                int m3 = (c + 127) >> 7;
                for (int mt = 0; mt < m3; mt++) jobs3[nj3++] = e2 * 64 + mt;
            }
            njobs[0] = nj2;
            njobs[1] = nj3;
        }
    }
}

// ---------------- conv: fp32 -> bf16 (dw, grid-stride; after k2, dwb aliases gwb) ----------------
constexpr int KCONV_BLOCKS = 1024;
__global__ __launch_bounds__(256) void k_conv(const float* __restrict__ in,
                                              __bf16* __restrict__ out, int n4) {
    int stride = KCONV_BLOCKS * 256;
    for (int i = blockIdx.x * 256 + threadIdx.x; i < n4; i += stride) {
        float4 v = ((const float4*)in)[i];
        bf16x4 o = {(__bf16)v.x, (__bf16)v.y, (__bf16)v.z, (__bf16)v.w};
        ((bf16x4*)out)[i] = o;
    }
}

// ---------------- k2: grouped GEMM gate+up, 8-phase counted-vmcnt schedule ----------------
// Tile 256(tokens) x 128(dff); B combined = [gate 128 rows; up 128 rows] x K.
// 512 threads = 8 waves (2M x 4N). Wave A-rows INTERLEAVED across tile halves:
// frag i rows = (i>>2)*128 + wm*64 + (i&3)*16  -> A-half h dies after its ih-phases.
// LDS 128 KB: A[2][256x64] + B[2][256x64], double-buffered by K-tile parity
// (even tiles -> buf0, odd -> buf1; static addressing).
// Per iter (2 K-tiles, 8 phases): each phase = {8|4 ds_read_b128, stage 1 half-tile
// (2 gload16), barrier, lgkmcnt(0)+sched_barrier, setprio(1), 16 MFMA, setprio(0),
// [vmcnt(4) at ph 1/4/5/8], barrier}. Loads never drained to 0 in the loop (T3+T4).
__global__ __launch_bounds__(512, 2) void k2_gateup(
    const __bf16* __restrict__ xb, const __bf16* __restrict__ gwb,
    const __bf16* __restrict__ uwb, const int* __restrict__ cnt,
    const int* __restrict__ off, const int* __restrict__ token_list,
    const int* __restrict__ jobs2, const int* __restrict__ njobs,
    __bf16* __restrict__ h) {
    int jt = blockIdx.x >> 4, nt = blockIdx.x & 15;   // nt: 0..15 (DFF/128)
    if (jt >= njobs[0]) return;
    int job = jobs2[jt];
    int e = job >> 6, mt = job & 63;
    int Me = cnt[e], offe = off[e];

    __shared__ __bf16 smA[2][16384];   // 64 KB: [buf][256 rows x 64]
    __shared__ __bf16 smB[2][16384];   // 64 KB: rows 0..127 gate, 128..255 up

    int tid = threadIdx.x;
    int lane = tid & 63, w = tid >> 6;
    int wm = w >> 2, wn = w & 3;          // 2M x 4N waves
    int kq = lane >> 4, m15 = lane & 15;

    // ---- staging source pointers (pre-swizzled global, linear LDS dest) ----
    // slot l2 = q*512+tid: row = l2>>3, sl = l2&7, source chunk = sl^(row&7)
    const __bf16 *aptr00, *aptr01, *aptr10, *aptr11;   // [h][q]
    const __bf16 *bptr00, *bptr01, *bptr10, *bptr11;   // h=0 gate, h=1 up
    {
        int l20 = tid,       rl0 = l20 >> 3, ch0 = (l20 & 7) ^ (rl0 & 7);
        int l21 = 512 + tid, rl1 = l21 >> 3, ch1 = (l21 & 7) ^ (rl1 & 7);
        int g00 = mt * 256 + rl0;       if (g00 >= Me) g00 = Me - 1;
        int g01 = mt * 256 + rl1;       if (g01 >= Me) g01 = Me - 1;
        int g10 = mt * 256 + 128 + rl0; if (g10 >= Me) g10 = Me - 1;
        int g11 = mt * 256 + 128 + rl1; if (g11 >= Me) g11 = Me - 1;
        aptr00 = xb + (size_t)token_list[e * T + g00] * H + ch0 * 8;
        aptr01 = xb + (size_t)token_list[e * T + g01] * H + ch1 * 8;
        aptr10 = xb + (size_t)token_list[e * T + g10] * H + ch0 * 8;
        aptr11 = xb + (size_t)token_list[e * T + g11] * H + ch1 * 8;
        size_t wb0 = ((size_t)e * DFF + nt * 128 + rl0) * H + ch0 * 8;
        size_t wb1 = ((size_t)e * DFF + nt * 128 + rl1) * H + ch1 * 8;
        bptr00 = gwb + wb0; bptr01 = gwb + wb1;
        bptr10 = uwb + wb0; bptr11 = uwb + wb1;
    }

#define STAGE_A0(KK, BUF) { gload16(aptr00 + (KK)*64, &smA[BUF][tid*8]); \
                            gload16(aptr01 + (KK)*64, &smA[BUF][4096 + tid*8]); }
#define STAGE_A1(KK, BUF) { gload16(aptr10 + (KK)*64, &smA[BUF][8192 + tid*8]); \
                            gload16(aptr11 + (KK)*64, &smA[BUF][8192 + 4096 + tid*8]); }
#define STAGE_B0(KK, BUF) { gload16(bptr00 + (KK)*64, &smB[BUF][tid*8]); \
                            gload16(bptr01 + (KK)*64, &smB[BUF][4096 + tid*8]); }
#define STAGE_B1(KK, BUF) { gload16(bptr10 + (KK)*64, &smB[BUF][8192 + tid*8]); \
                            gload16(bptr11 + (KK)*64, &smB[BUF][8192 + 4096 + tid*8]); }

    // ---- ds_read lane constants ----
    int slb0 = ((0 + kq) ^ (m15 & 7)) * 8;   // kc=0 chunk-slot (elements)
    int slb1 = ((4 + kq) ^ (m15 & 7)) * 8;   // kc=1
    int arow = wm * 64 + m15;                // + i2*16 + ih*128
    int brow = wn * 32 + m15;                // + j*16 (+128 up)

    f32x4 accg[8][2] = {};
    f32x4 accu[8][2] = {};
    bf16x8 af[4], gf[2], uf[2];

#define LDA4(BUF, IH, SLB) { \
    af[0] = *(const bf16x8*)&smA[BUF][(arow + (IH)*128 +  0)*64 + (SLB)]; \
    af[1] = *(const bf16x8*)&smA[BUF][(arow + (IH)*128 + 16)*64 + (SLB)]; \
    af[2] = *(const bf16x8*)&smA[BUF][(arow + (IH)*128 + 32)*64 + (SLB)]; \
    af[3] = *(const bf16x8*)&smA[BUF][(arow + (IH)*128 + 48)*64 + (SLB)]; }
#define LDB4(BUF, SLB) { \
    gf[0] = *(const bf16x8*)&smB[BUF][(brow +   0)*64 + (SLB)]; \
    gf[1] = *(const bf16x8*)&smB[BUF][(brow +  16)*64 + (SLB)]; \
    uf[0] = *(const bf16x8*)&smB[BUF][(brow + 128)*64 + (SLB)]; \
    uf[1] = *(const bf16x8*)&smB[BUF][(brow + 144)*64 + (SLB)]; }
#define MFMA16(IH) { \
    _Pragma("unroll") \
    for (int i2 = 0; i2 < 4; i2++) { \
        _Pragma("unroll") \
        for (int j = 0; j < 2; j++) { \
            accg[(IH)*4 + i2][j] = __builtin_amdgcn_mfma_f32_16x16x32_bf16(af[i2], gf[j], accg[(IH)*4 + i2][j], 0, 0, 0); \
            accu[(IH)*4 + i2][j] = __builtin_amdgcn_mfma_f32_16x16x32_bf16(af[i2], uf[j], accu[(IH)*4 + i2][j], 0, 0, 0); \
        } } }
#define PH_SYNC  { __builtin_amdgcn_s_barrier(); \
                   asm volatile("s_waitcnt lgkmcnt(0)" ::: "memory"); \
                   __builtin_amdgcn_sched_barrier(0); \
                   __builtin_amdgcn_s_setprio(1); }
#define PH_ENDVM { __builtin_amdgcn_s_setprio(0); \
                   asm volatile("s_waitcnt vmcnt(4)" ::: "memory"); \
                   __builtin_amdgcn_s_barrier(); }
#define PH_END   { __builtin_amdgcn_s_setprio(0); \
                   __builtin_amdgcn_s_barrier(); }

    // ---- prologue: match steady-state issue history ----
    // [Ah0(0),Bh0(0),Bh1(0),Ah1(0) -> buf0, Ah0(1) -> buf1]; wait first 3 halves.
    STAGE_A0(0, 0); STAGE_B0(0, 0); STAGE_B1(0, 0); STAGE_A1(0, 0);
    STAGE_A0(1, 1);
    asm volatile("s_waitcnt vmcnt(4)" ::: "memory");
    __builtin_amdgcn_s_barrier();

    // ---- main loop: 8 iters x 2 K-tiles (K=1024, BK=64) ----
    for (int i = 0; i < 8; ++i) {
        int kb  = 2 * i + 1;          // odd tile staged ph1-3 (always <= 15)
        int ka2 = (2 * i + 2) & 15;   // next even tile (wraps harmlessly)
        int kb2 = (2 * i + 3) & 15;   // next odd tile

        // ph1: tile a=2i (buf0), ih0, kc0 | stage Bh0(b)->buf1 | vm
        LDA4(0, 0, slb0); LDB4(0, slb0);
        STAGE_B0(kb, 1);
        PH_SYNC; MFMA16(0); PH_ENDVM;
        // ph2: ih1, kc0 (reuse B kc0) | stage Bh1(b)->buf1
        LDA4(0, 1, slb0);
        STAGE_B1(kb, 1);
        PH_SYNC; MFMA16(1); PH_END;
        // ph3: ih0, kc1 | stage Ah1(b)->buf1
        LDA4(0, 0, slb1); LDB4(0, slb1);
        STAGE_A1(kb, 1);
        PH_SYNC; MFMA16(0); PH_END;
        // ph4: ih1, kc1 | stage Ah0(a')->buf0 | vm
        LDA4(0, 1, slb1);
        STAGE_A0(ka2, 0);
        PH_SYNC; MFMA16(1); PH_ENDVM;
        // ph5: tile b=2i+1 (buf1), ih0, kc0 | stage Bh0(a')->buf0 | vm
        LDA4(1, 0, slb0); LDB4(1, slb0);
        STAGE_B0(ka2, 0);
        PH_SYNC; MFMA16(0); PH_ENDVM;
        // ph6: ih1, kc0 | stage Bh1(a')->buf0
        LDA4(1, 1, slb0);
        STAGE_B1(ka2, 0);
        PH_SYNC; MFMA16(1); PH_END;
        // ph7: ih0, kc1 | stage Ah1(a')->buf0
        LDA4(1, 0, slb1); LDB4(1, slb1);
        STAGE_A1(ka2, 0);
        PH_SYNC; MFMA16(0); PH_END;
        // ph8: ih1, kc1 | stage Ah0(b')->buf1 | vm
        LDA4(1, 1, slb1);
        STAGE_A0(kb2, 1);
        PH_SYNC; MFMA16(1); PH_ENDVM;
    }

    // ---- epilogue: h = silu(g) * u, in-register g/u pairing ----
    #pragma unroll
    for (int i = 0; i < 8; i++) {
        int ih = i >> 2, i2 = i & 3;
        #pragma unroll
        for (int j = 0; j < 2; j++) {
            int c = nt * 128 + wn * 32 + j * 16 + m15;
            #pragma unroll
            for (int p = 0; p < 4; p++) {
                int mloc = ih * 128 + wm * 64 + i2 * 16 + kq * 4 + p;
                int mrow = mt * 256 + mloc;
                if (mrow < Me) {
                    float g = accg[i][j][p], u = accu[i][j][p];
                    float sig = 1.0f / (1.0f + __expf(-g));
                    h[(size_t)(offe + mrow) * DFF + c] = (__bf16)(g * sig * u);
                }
            }
        }
    }
#undef STAGE_A0
#undef STAGE_A1
#undef STAGE_B0
#undef STAGE_B1
#undef LDA4
#undef LDB4
#undef MFMA16
#undef PH_SYNC
#undef PH_ENDVM
#undef PH_END
}

// ---------------- k3: grouped GEMM down (MFMA), BK=64, tile 128x128. FROZEN. ----------------
__global__ __launch_bounds__(256, 2) void k3_down(
    const __bf16* __restrict__ h, const __bf16* __restrict__ dwb,
    const int* __restrict__ cnt, const int* __restrict__ off,
    const int* __restrict__ jobs3, const int* __restrict__ njobs,
    __bf16* __restrict__ y) {
    int jt = blockIdx.x >> 3, nt = blockIdx.x & 7;    // nt: 0..7 (H/128)
    if (jt >= njobs[1]) return;
    int job = jobs3[jt];
    int e = job >> 6, mt = job & 63;
    int Me = cnt[e], offe = off[e];

    __shared__ __bf16 As[128 * 64];   // 16 KB
    __shared__ __bf16 Bs[128 * 64];   // 16 KB

    int tid = threadIdx.x;
    int lane = tid & 63, w = tid >> 6;
    int wm = w >> 1, wn = w & 1;

    const __bf16* asrc[4];
    const __bf16* bsrc[4];
    #pragma unroll
    for (int rr = 0; rr < 4; rr++) {
        int l = rr * 256 + tid;
        int row = l >> 3, sl = l & 7;
        int koff = (sl ^ (row & 7)) * 8;
        int gr = mt * 128 + row; if (gr >= Me) gr = Me - 1;
        asrc[rr] = h + (size_t)(offe + gr) * DFF + koff;
        bsrc[rr] = dwb + ((size_t)e * H + nt * 128 + row) * DFF + koff;
    }

    f32x4 acc[4][4] = {};
    int kq = lane >> 4, m15 = lane & 15;

    for (int k0 = 0; k0 < DFF; k0 += 64) {
        #pragma unroll
        for (int rr = 0; rr < 4; rr++)
            gload16(asrc[rr] + k0, &As[(rr * 256 + tid) * 8]);
        #pragma unroll
        for (int rr = 0; rr < 4; rr++)
            gload16(bsrc[rr] + k0, &Bs[(rr * 256 + tid) * 8]);
        __syncthreads();

        #pragma unroll
        for (int kc = 0; kc < 2; kc++) {
            bf16x8 af[4], bf[4];
            #pragma unroll
            for (int i = 0; i < 4; i++) {
                int row = wm * 64 + i * 16 + m15;
                int sl = (kc * 4 + kq) ^ (row & 7);
                af[i] = *(const bf16x8*)&As[row * 64 + sl * 8];
            }
            #pragma unroll
            for (int j = 0; j < 4; j++) {
                int row = wn * 64 + j * 16 + m15;
                int sl = (kc * 4 + kq) ^ (row & 7);
                bf[j] = *(const bf16x8*)&Bs[row * 64 + sl * 8];
            }
            #pragma unroll
            for (int i = 0; i < 4; i++)
                #pragma unroll
                for (int j = 0; j < 4; j++)
                    acc[i][j] = __builtin_amdgcn_mfma_f32_16x16x32_bf16(af[i], bf[j], acc[i][j], 0, 0, 0);
        }
        __syncthreads();
    }

    #pragma unroll
    for (int i = 0; i < 4; i++)
        #pragma unroll
        for (int j = 0; j < 4; j++) {
            int nglob = nt * 128 + wn * 64 + j * 16 + m15;
            #pragma unroll
            for (int p = 0; p < 4; p++) {
                int mloc = wm * 64 + i * 16 + kq * 4 + p;
                int mrow = mt * 128 + mloc;
                if (mrow < Me)
                    y[(size_t)(offe + mrow) * H + nglob] = (__bf16)acc[i][j][p];
            }
        }
}

// ---------------- gather: weighted top-2 combine -> out ----------------
__global__ __launch_bounds__(256) void k_gather(
    const __bf16* __restrict__ y, const int* __restrict__ se,
    const int* __restrict__ sp, const float* __restrict__ sw,
    const int* __restrict__ off, float* __restrict__ out) {
    int t = blockIdx.x;
    int r0 = off[se[2 * t]] + sp[2 * t];
    int r1 = off[se[2 * t + 1]] + sp[2 * t + 1];
    float w0 = sw[2 * t], w1 = sw[2 * t + 1];
    const bf16x4* y0 = (const bf16x4*)(y + (size_t)r0 * H);
    const bf16x4* y1 = (const bf16x4*)(y + (size_t)r1 * H);
    float4* o = (float4*)(out + (size_t)t * H);
    int c = threadIdx.x;
    bf16x4 a = y0[c], b = y1[c];
    float4 v;
    v.x = w0 * (float)a[0] + w1 * (float)b[0];
    v.y = w0 * (float)a[1] + w1 * (float)b[1];
    v.z = w0 * (float)a[2] + w1 * (float)b[2];
    v.w = w0 * (float)a[3] + w1 * (float)b[3];
    o[c] = v;
}

// ---------------- launch ----------------
extern "C" void kernel_launch(void* const* d_in, const int* in_sizes, int n_in,
                              void* d_out, int out_size, void* d_ws, size_t ws_size,
                              hipStream_t stream) {
    const float* x    = (const float*)d_in[0];
    const float* cent = (const float*)d_in[1];
    const float* gw   = (const float*)d_in[2];
    const float* uw   = (const float*)d_in[3];
    const float* dw   = (const float*)d_in[4];
    const float* bias = (const float*)d_in[5];
    float* out = (float*)d_out;

    // workspace layout (bytes) — compact aliased layout (105 MB top)
    char* ws = (char*)d_ws;
    int*   cnt        = (int*)(ws + 0);
    int*   off        = (int*)(ws + 64);
    int*   se         = (int*)(ws + 128);              // 32 KB
    int*   sp         = (int*)(ws + 128 + 32768);      // 32 KB
    float* sw         = (float*)(ws + 128 + 65536);    // 32 KB
    int*   token_list = (int*)(ws + 128 + 98304);      // 128 KB
    int*   jobs2      = (int*)(ws + 229504);           // 40 ints
    int*   jobs3      = (int*)(ws + 229760);           // 72 ints
    int*   njobs      = (int*)(ws + 230144);           // 2 ints
    int*   done       = (int*)(ws + 230208);           // 1 int
    const size_t MB = 1u << 20;
    __bf16* gwb = (__bf16*)(ws + 1 * MB);              // 32 MB
    __bf16* uwb = (__bf16*)(ws + 1 * MB + 33554432);   // 32 MB
    __bf16* dwb = gwb;                                 // alias: converted after k2
    __bf16* y   = uwb;                                 // alias: uwb dead after k2
    __bf16* xb  = (__bf16*)(ws + 1 * MB + 67108864);   // 8 MB
    __bf16* h   = (__bf16*)(ws + 1 * MB + 75497472);   // 32 MB (top = 105 MB)

    const int W4 = E * DFF * H / 4;
    const int X4 = T * H / 4;

    k0_fused<<<1024 + CONV_BLOCKS, 256, 0, stream>>>(
        x, cent, bias, se, sw, gw, gwb, uw, uwb, xb, W4, X4, done);
    k1b_partition<<<E, 1024, 0, stream>>>(se, token_list, sp, cnt,
                                          off, out + (size_t)T * H, jobs2, jobs3, njobs, done);
    k2_gateup<<<MAXJ2 * 16, 512, 0, stream>>>(xb, gwb, uwb, cnt, off, token_list, jobs2, njobs, h);
    k_conv<<<KCONV_BLOCKS, 256, 0, stream>>>(dw, dwb, W4);  // aliases gwb; after k2
    k3_down<<<MAXJ3 * 8, 256, 0, stream>>>(h, dwb, cnt, off, jobs3, njobs, y);
    k_gather<<<T, 256, 0, stream>>>(y, se, sp, sw, off, out);
}

// Round 8
// 392.899 us; speedup vs baseline: 1.0149x; 1.0149x over previous
//
#include <hip/hip_runtime.h>
#include <math.h>

// Problem constants
constexpr int E = 8, H = 1024, DFF = 2048, T = 4096;
constexpr int TR = 8192;          // total routed rows = T * topk
constexpr int MAXJ = 72;          // max (expert, m-tile) jobs: 8192/128 + E

typedef __bf16 bf16x8 __attribute__((ext_vector_type(8)));
typedef __bf16 bf16x4 __attribute__((ext_vector_type(4)));
typedef float f32x4 __attribute__((ext_vector_type(4)));

__device__ __forceinline__ void gload16(const void* g, void* l) {
    __builtin_amdgcn_global_load_lds(
        (const __attribute__((address_space(1))) unsigned int*)g,
        (__attribute__((address_space(3))) unsigned int*)l, 16, 0, 0);
}

// ---------------- k0: fused conversions (gw,uw,x -> bf16) + out-zero + affinity ----------------
// blocks [0,1024): affinity; blocks [1024, 1024+3072): grid-stride conversion+zero.
constexpr int CONV_BLOCKS = 3072;
__global__ __launch_bounds__(256) void k0_fused(
    const float* __restrict__ x, const float* __restrict__ cent,
    const float* __restrict__ bias,
    int* __restrict__ se, float* __restrict__ sw,
    const float* __restrict__ gw, __bf16* __restrict__ gwb,
    const float* __restrict__ uw, __bf16* __restrict__ uwb,
    __bf16* __restrict__ xb, float* __restrict__ outz,
    int w4, int x4, int o4, int* __restrict__ done) {
    __shared__ float cs[E * H];
    int tid = threadIdx.x;

    if (blockIdx.x == 0 && tid == 0) *done = 0;   // reset for k1b's last-block pattern

    if (blockIdx.x >= 1024) {
        // conversion + out-zero role: grid-stride over [0, 2*w4 + x4 + o4) float4s
        int total = 2 * w4 + x4 + o4;
        int stride = CONV_BLOCKS * 256;
        for (int i = (blockIdx.x - 1024) * 256 + tid; i < total; i += stride) {
            if (i >= 2 * w4 + x4) {
                // zero the output accumulator region [0, T*H)
                float4 z = {0.f, 0.f, 0.f, 0.f};
                ((float4*)outz)[i - 2 * w4 - x4] = z;
                continue;
            }
            const float* in; __bf16* outp; int idx;
            if (i < w4) { in = gw; outp = gwb; idx = i; }
            else if (i < 2 * w4) { in = uw; outp = uwb; idx = i - w4; }
            else { in = x; outp = xb; idx = i - 2 * w4; }
            float4 v = ((const float4*)in)[idx];
            bf16x4 o = {(__bf16)v.x, (__bf16)v.y, (__bf16)v.z, (__bf16)v.w};
            ((bf16x4*)outp)[idx] = o;
        }
        return;
    }

    // affinity role
    for (int i = tid; i < E * H / 4; i += 256)
        ((float4*)cs)[i] = ((const float4*)cent)[i];
    __syncthreads();

    int wave = tid >> 6, lane = tid & 63;
    int t = blockIdx.x * 4 + wave;
    const float4* xr = (const float4*)(x + (size_t)t * H);
    float acc[E] = {};
    #pragma unroll
    for (int it = 0; it < 4; it++) {
        float4 xv = xr[lane + it * 64];
        #pragma unroll
        for (int e = 0; e < E; e++) {
            float4 cv = ((const float4*)(cs + e * H))[lane + it * 64];
            acc[e] = fmaf(xv.x, cv.x, acc[e]);
            acc[e] = fmaf(xv.y, cv.y, acc[e]);
            acc[e] = fmaf(xv.z, cv.z, acc[e]);
            acc[e] = fmaf(xv.w, cv.w, acc[e]);
        }
    }
    #pragma unroll
    for (int off = 32; off; off >>= 1)
        #pragma unroll
        for (int e = 0; e < E; e++) acc[e] += __shfl_down(acc[e], off);

    if (lane == 0) {
        float s[E];
        #pragma unroll
        for (int e = 0; e < E; e++)
            s[e] = 1.0f / (1.0f + expf(-acc[e])) + bias[e];
        int i0 = 0;
        for (int e = 1; e < E; e++) if (s[e] > s[i0]) i0 = e;
        int i1 = -1;
        for (int e = 0; e < E; e++) {
            if (e == i0) continue;
            if (i1 < 0 || s[e] > s[i1]) i1 = e;
        }
        float m = fmaxf(s[i0], s[i1]);
        float w0 = expf(s[i0] - m), w1 = expf(s[i1] - m);
        float inv = 1.0f / (w0 + w1);
        se[2 * t] = i0;     sw[2 * t] = w0 * inv;
        se[2 * t + 1] = i1; sw[2 * t + 1] = w1 * inv;
    }
}

// ---------------- k1b: per-expert partition (+ per-row weight) + (last block) offsets/jobs ----------------
__global__ __launch_bounds__(1024) void k1b_partition(
    const int* __restrict__ se, const float* __restrict__ sw,
    int* __restrict__ token_list, float* __restrict__ wlist,
    int* __restrict__ cnt,
    int* __restrict__ off, float* __restrict__ out_counts,
    int* __restrict__ jobs, int* __restrict__ njobs, int* __restrict__ done) {
    int e = blockIdx.x;
    int tid = threadIdx.x;
    int wave = tid >> 6, lane = tid & 63;
    __shared__ int wsum[16];
    int running = 0;
    for (int c0 = 0; c0 < 2 * T; c0 += 1024) {
        int i = c0 + tid;
        bool pred = (se[i] == e);
        unsigned long long mask = __ballot(pred);
        int pos_in_wave = __popcll(mask & ((1ull << lane) - 1ull));
        if (lane == 0) wsum[wave] = __popcll(mask);
        __syncthreads();
        int wbase = 0;
        #pragma unroll
        for (int w2 = 0; w2 < 16; w2++) {
            int v = wsum[w2];
            if (w2 < wave) wbase += v;
        }
        int total = 0;
        #pragma unroll
        for (int w2 = 0; w2 < 16; w2++) total += wsum[w2];
        if (pred) {
            int p = running + wbase + pos_in_wave;
            token_list[e * T + p] = i >> 1;
            wlist[e * T + p] = sw[i];
        }
        running += total;
        __syncthreads();
    }
    if (tid == 0) {
        __hip_atomic_store(&cnt[e], running, __ATOMIC_RELEASE, __HIP_MEMORY_SCOPE_AGENT);
        int prev = __hip_atomic_fetch_add(done, 1, __ATOMIC_ACQ_REL, __HIP_MEMORY_SCOPE_AGENT);
        if (prev == E - 1) {
            int acc = 0, nj = 0;
            for (int e2 = 0; e2 < E; e2++) {
                int c = __hip_atomic_load(&cnt[e2], __ATOMIC_ACQUIRE, __HIP_MEMORY_SCOPE_AGENT);
                off[e2] = acc; acc += c;
                out_counts[e2] = (float)c;
                int mts = (c + 127) >> 7;
                for (int mt = 0; mt < mts; mt++) jobs[nj++] = e2 * 64 + mt;
            }
            njobs[0] = nj;
        }
    }
}

// ---------------- conv: fp32 -> bf16 (dw, grid-stride; after k2, dwb aliases gwb) ----------------
constexpr int KCONV_BLOCKS = 1024;
__global__ __launch_bounds__(256) void k_conv(const float* __restrict__ in,
                                              __bf16* __restrict__ out, int n4) {
    int stride = KCONV_BLOCKS * 256;
    for (int i = blockIdx.x * 256 + threadIdx.x; i < n4; i += stride) {
        float4 v = ((const float4*)in)[i];
        bf16x4 o = {(__bf16)v.x, (__bf16)v.y, (__bf16)v.z, (__bf16)v.w};
        ((bf16x4*)out)[i] = o;
    }
}

// ---------------- k2: grouped GEMM gate+up (MFMA), BK=64, tile 128x128 dual ----------------
// PROVEN: 94 us, MfmaUtil 32%, VGPR 108 (rounds 0/2/6). FROZEN.
__global__ __launch_bounds__(256, 2) void k2_gateup(
    const __bf16* __restrict__ xb, const __bf16* __restrict__ gwb,
    const __bf16* __restrict__ uwb, const int* __restrict__ cnt,
    const int* __restrict__ off, const int* __restrict__ token_list,
    const int* __restrict__ jobs, const int* __restrict__ njobs,
    __bf16* __restrict__ h) {
    int jt = blockIdx.x >> 4, nt = blockIdx.x & 15;   // nt: 0..15 (DFF/128)
    if (jt >= njobs[0]) return;
    int job = jobs[jt];
    int e = job >> 6, mt = job & 63;
    int Me = cnt[e], offe = off[e];

    __shared__ __bf16 As[128 * 64];   // 16 KB
    __shared__ __bf16 Bg[128 * 64];   // 16 KB
    __shared__ __bf16 Bu[128 * 64];   // 16 KB

    int tid = threadIdx.x;
    int lane = tid & 63, w = tid >> 6;
    int wm = w >> 1, wn = w & 1;

    const __bf16* asrc[4];
    const __bf16 *bsg[4], *bsu[4];
    #pragma unroll
    for (int rr = 0; rr < 4; rr++) {
        int l = rr * 256 + tid;
        int row = l >> 3, sl = l & 7;
        int gr = mt * 128 + row; if (gr >= Me) gr = Me - 1;
        int tok = token_list[e * T + gr];
        asrc[rr] = xb + (size_t)tok * H + ((sl ^ (row & 7)) * 8);
        size_t base = ((size_t)e * DFF + nt * 128 + row) * H + ((sl ^ (row & 7)) * 8);
        bsg[rr] = gwb + base;
        bsu[rr] = uwb + base;
    }

    f32x4 accg[4][4] = {};
    f32x4 accu[4][4] = {};
    int kq = lane >> 4, m15 = lane & 15;

    for (int k0 = 0; k0 < H; k0 += 64) {
        #pragma unroll
        for (int rr = 0; rr < 4; rr++) {
            gload16(asrc[rr] + k0, &As[(rr * 256 + tid) * 8]);
            gload16(bsg[rr] + k0, &Bg[(rr * 256 + tid) * 8]);
            gload16(bsu[rr] + k0, &Bu[(rr * 256 + tid) * 8]);
        }
        __syncthreads();

        #pragma unroll
        for (int kc = 0; kc < 2; kc++) {
            bf16x8 af[4], gf[4], uf[4];
            #pragma unroll
            for (int i = 0; i < 4; i++) {
                int row = wm * 64 + i * 16 + m15;
                int sl = (kc * 4 + kq) ^ (row & 7);
                af[i] = *(const bf16x8*)&As[row * 64 + sl * 8];
            }
            #pragma unroll
            for (int j = 0; j < 4; j++) {
                int row = wn * 64 + j * 16 + m15;
                int sl = (kc * 4 + kq) ^ (row & 7);
                gf[j] = *(const bf16x8*)&Bg[row * 64 + sl * 8];
                uf[j] = *(const bf16x8*)&Bu[row * 64 + sl * 8];
            }
            #pragma unroll
            for (int i = 0; i < 4; i++)
                #pragma unroll
                for (int j = 0; j < 4; j++) {
                    accg[i][j] = __builtin_amdgcn_mfma_f32_16x16x32_bf16(af[i], gf[j], accg[i][j], 0, 0, 0);
                    accu[i][j] = __builtin_amdgcn_mfma_f32_16x16x32_bf16(af[i], uf[j], accu[i][j], 0, 0, 0);
                }
        }
        __syncthreads();
    }

    // epilogue: h = silu(g) * u
    #pragma unroll
    for (int i = 0; i < 4; i++)
        #pragma unroll
        for (int j = 0; j < 4; j++) {
            int nloc = wn * 64 + j * 16 + m15;
            size_t c = (size_t)nt * 128 + nloc;
            #pragma unroll
            for (int p = 0; p < 4; p++) {
                int mloc = wm * 64 + i * 16 + kq * 4 + p;
                int mrow = mt * 128 + mloc;
                if (mrow < Me) {
                    float g = accg[i][j][p], u = accu[i][j][p];
                    float sig = 1.0f / (1.0f + __expf(-g));
                    h[(size_t)(offe + mrow) * DFF + c] = (__bf16)(g * sig * u);
                }
            }
        }
}

// ---------------- k3: grouped GEMM down (MFMA), BK=64, tile 128x128 ----------------
// Main loop FROZEN. Epilogue fused with the top-2 weighted combine:
// out[tok] += w * acc (f32 atomics; exactly 2 commutative adds per element).
__global__ __launch_bounds__(256, 2) void k3_down(
    const __bf16* __restrict__ h, const __bf16* __restrict__ dwb,
    const int* __restrict__ cnt, const int* __restrict__ off,
    const int* __restrict__ token_list, const float* __restrict__ wlist,
    const int* __restrict__ jobs, const int* __restrict__ njobs,
    float* __restrict__ out) {
    int jt = blockIdx.x >> 3, nt = blockIdx.x & 7;    // nt: 0..7 (H/128)
    if (jt >= njobs[0]) return;
    int job = jobs[jt];
    int e = job >> 6, mt = job & 63;
    int Me = cnt[e], offe = off[e];

    __shared__ __bf16 As[128 * 64];   // 16 KB
    __shared__ __bf16 Bs[128 * 64];   // 16 KB

    int tid = threadIdx.x;
    int lane = tid & 63, w = tid >> 6;
    int wm = w >> 1, wn = w & 1;

    const __bf16* asrc[4];
    const __bf16* bsrc[4];
    #pragma unroll
    for (int rr = 0; rr < 4; rr++) {
        int l = rr * 256 + tid;
        int row = l >> 3, sl = l & 7;
        int koff = (sl ^ (row & 7)) * 8;
        int gr = mt * 128 + row; if (gr >= Me) gr = Me - 1;
        asrc[rr] = h + (size_t)(offe + gr) * DFF + koff;
        bsrc[rr] = dwb + ((size_t)e * H + nt * 128 + row) * DFF + koff;
    }

    f32x4 acc[4][4] = {};
    int kq = lane >> 4, m15 = lane & 15;

    for (int k0 = 0; k0 < DFF; k0 += 64) {
        #pragma unroll
        for (int rr = 0; rr < 4; rr++)
            gload16(asrc[rr] + k0, &As[(rr * 256 + tid) * 8]);
        #pragma unroll
        for (int rr = 0; rr < 4; rr++)
            gload16(bsrc[rr] + k0, &Bs[(rr * 256 + tid) * 8]);
        __syncthreads();

        #pragma unroll
        for (int kc = 0; kc < 2; kc++) {
            bf16x8 af[4], bf[4];
            #pragma unroll
            for (int i = 0; i < 4; i++) {
                int row = wm * 64 + i * 16 + m15;
                int sl = (kc * 4 + kq) ^ (row & 7);
                af[i] = *(const bf16x8*)&As[row * 64 + sl * 8];
            }
            #pragma unroll
            for (int j = 0; j < 4; j++) {
                int row = wn * 64 + j * 16 + m15;
                int sl = (kc * 4 + kq) ^ (row & 7);
                bf[j] = *(const bf16x8*)&Bs[row * 64 + sl * 8];
            }
            #pragma unroll
            for (int i = 0; i < 4; i++)
                #pragma unroll
                for (int j = 0; j < 4; j++)
                    acc[i][j] = __builtin_amdgcn_mfma_f32_16x16x32_bf16(af[i], bf[j], acc[i][j], 0, 0, 0);
        }
        __syncthreads();
    }

    // fused epilogue: weighted atomic accumulate into out
    #pragma unroll
    for (int i = 0; i < 4; i++) {
        #pragma unroll
        for (int p = 0; p < 4; p++) {
            int mloc = wm * 64 + i * 16 + kq * 4 + p;
            int mrow = mt * 128 + mloc;
            if (mrow < Me) {
                int tok = token_list[e * T + mrow];
                float wgt = wlist[e * T + mrow];
                float* orow = out + (size_t)tok * H;
                #pragma unroll
                for (int j = 0; j < 4; j++) {
                    int nglob = nt * 128 + wn * 64 + j * 16 + m15;
                    atomicAdd(&orow[nglob], wgt * acc[i][j][p]);
                }
            }
        }
    }
}

// ---------------- launch ----------------
extern "C" void kernel_launch(void* const* d_in, const int* in_sizes, int n_in,
                              void* d_out, int out_size, void* d_ws, size_t ws_size,
                              hipStream_t stream) {
    const float* x    = (const float*)d_in[0];
    const float* cent = (const float*)d_in[1];
    const float* gw   = (const float*)d_in[2];
    const float* uw   = (const float*)d_in[3];
    const float* dw   = (const float*)d_in[4];
    const float* bias = (const float*)d_in[5];
    float* out = (float*)d_out;

    // workspace layout (bytes) — compact aliased layout
    char* ws = (char*)d_ws;
    int*   cnt        = (int*)(ws + 0);
    int*   off        = (int*)(ws + 64);
    int*   se         = (int*)(ws + 128);               // 32 KB
    float* sw         = (float*)(ws + 128 + 32768);     // 32 KB
    int*   token_list = (int*)(ws + 128 + 65536);       // 128 KB
    float* wlist      = (float*)(ws + 128 + 196608);    // 128 KB
    int*   jobs       = (int*)(ws + 327808);            // 80 ints
    int*   njobs      = (int*)(ws + 328128);            // 1 int
    int*   done       = (int*)(ws + 328192);            // 1 int
    const size_t MB = 1u << 20;
    __bf16* gwb = (__bf16*)(ws + 1 * MB);               // 32 MB
    __bf16* uwb = (__bf16*)(ws + 1 * MB + 33554432);    // 32 MB
    __bf16* dwb = gwb;                                  // alias: converted after k2
    __bf16* xb  = (__bf16*)(ws + 1 * MB + 67108864);    // 8 MB
    __bf16* h   = (__bf16*)(ws + 1 * MB + 75497472);    // 32 MB (top = 105 MB)

    const int W4 = E * DFF * H / 4;
    const int X4 = T * H / 4;
    const int O4 = T * H / 4;

    k0_fused<<<1024 + CONV_BLOCKS, 256, 0, stream>>>(
        x, cent, bias, se, sw, gw, gwb, uw, uwb, xb, out, W4, X4, O4, done);
    k1b_partition<<<E, 1024, 0, stream>>>(se, sw, token_list, wlist, cnt,
                                          off, out + (size_t)T * H, jobs, njobs, done);
    k2_gateup<<<MAXJ * 16, 256, 0, stream>>>(xb, gwb, uwb, cnt, off, token_list, jobs, njobs, h);
    k_conv<<<KCONV_BLOCKS, 256, 0, stream>>>(dw, dwb, W4);  // aliases gwb; after k2
    k3_down<<<MAXJ * 8, 256, 0, stream>>>(h, dwb, cnt, off, token_list, wlist, jobs, njobs, out);
}